// Round 1
// baseline (4591.090 us; speedup 1.0000x reference)
//
#include <hip/hip_runtime.h>
#include <math.h>

#define B_   128
#define T_   1024
#define IN_  300
#define H_   300
#define OUT_ 300

// ---------------------------------------------------------------------------
// K1: C[m][n] = sum_k A[m][k] * W[n][k] + bias[n]
// A row-major (lda), W row-major (ldw) with column offset wcol0.
// Tiles: BM=64, BN=64, BK=32; 256 threads; 4x4 microtile.
// M must be a multiple of 64 (131072 is). N,K guarded.
// ---------------------------------------------------------------------------
__global__ __launch_bounds__(256) void gemm_bias_kernel(
    const float* __restrict__ A, int lda,
    const float* __restrict__ W, int ldw, int wcol0,
    const float* __restrict__ bias,
    float* __restrict__ C, int ldc,
    int N, int K)
{
    __shared__ float As[64][33];
    __shared__ float Ws[64][33];
    const int tid = threadIdx.x;
    const int tx = tid & 15;
    const int ty = tid >> 4;
    const size_t m0 = (size_t)blockIdx.x * 64;
    const int n0 = blockIdx.y * 64;

    float acc[4][4] = {};

    for (int kc = 0; kc < K; kc += 32) {
        #pragma unroll
        for (int i = 0; i < 8; ++i) {
            int e = tid + i * 256;          // 0..2047
            int r = e >> 5;
            int c = e & 31;
            int gk = kc + c;
            As[r][c] = (gk < K) ? A[(m0 + r) * (size_t)lda + gk] : 0.f;
            int wn = n0 + r;
            Ws[r][c] = (wn < N && gk < K) ? W[(size_t)wn * ldw + wcol0 + gk] : 0.f;
        }
        __syncthreads();
        #pragma unroll
        for (int k = 0; k < 32; ++k) {
            float a[4], w[4];
            #pragma unroll
            for (int i = 0; i < 4; ++i) a[i] = As[ty * 4 + i][k];
            #pragma unroll
            for (int j = 0; j < 4; ++j) w[j] = Ws[tx * 4 + j][k];
            #pragma unroll
            for (int i = 0; i < 4; ++i)
                #pragma unroll
                for (int j = 0; j < 4; ++j)
                    acc[i][j] = fmaf(a[i], w[j], acc[i][j]);
        }
        __syncthreads();
    }

    #pragma unroll
    for (int i = 0; i < 4; ++i) {
        size_t m = m0 + ty * 4 + i;
        #pragma unroll
        for (int j = 0; j < 4; ++j) {
            int n = n0 + tx * 4 + j;
            if (n < N) C[m * (size_t)ldc + n] = acc[i][j] + bias[n];
        }
    }
}

// ---------------------------------------------------------------------------
// K2: recurrence. One block per batch element; 640 threads (600 active).
// Thread (r,p): r = tid>>1 (h-row), p = tid&1 (column-half, interleaved by
// float4 chunks: cols 8j+4p+0..3). W1h row slice lives in 38 float4 VGPRs.
// h kept in LDS (304 floats, zero-padded). buf[b][t][:] holds A on entry and
// is overwritten with h after use (same thread, same address).
// ---------------------------------------------------------------------------
__global__ __launch_bounds__(640) void elman_rec_kernel(
    const float* __restrict__ W1,   // [300][600]; W1h = cols 300..599
    float* __restrict__ buf,        // [B][T][300] : A in, h out
    float* __restrict__ hfinal)     // [B][300]
{
    __shared__ float hbuf[304];
    const int b   = blockIdx.x;
    const int tid = threadIdx.x;
    const int r   = tid >> 1;
    const int p   = tid & 1;
    const bool active = (r < 300);

    // Load W1h slice into registers (zero-padded past col 299).
    float4 w[38];
    #pragma unroll
    for (int j = 0; j < 38; ++j) {
        float4 v = make_float4(0.f, 0.f, 0.f, 0.f);
        if (active) {
            const float* wr = W1 + (size_t)r * 600 + 300;
            int c0 = j * 8 + p * 4;
            if (c0 + 0 < 300) v.x = wr[c0 + 0];
            if (c0 + 1 < 300) v.y = wr[c0 + 1];
            if (c0 + 2 < 300) v.z = wr[c0 + 2];
            if (c0 + 3 < 300) v.w = wr[c0 + 3];
        }
        w[j] = v;
    }

    for (int i = tid; i < 304; i += 640) hbuf[i] = 0.f;
    __syncthreads();

    float* bp = buf + (size_t)b * T_ * 300;

    for (int t = 0; t < T_; ++t) {
        float aval = 0.f;
        if (active && p == 0) aval = bp[t * 300 + r];   // A[b,t,r]

        float4 acc4 = make_float4(0.f, 0.f, 0.f, 0.f);
        #pragma unroll
        for (int j = 0; j < 38; ++j) {
            const float4 h4 = *reinterpret_cast<const float4*>(&hbuf[j * 8 + p * 4]);
            acc4.x = fmaf(w[j].x, h4.x, acc4.x);
            acc4.y = fmaf(w[j].y, h4.y, acc4.y);
            acc4.z = fmaf(w[j].z, h4.z, acc4.z);
            acc4.w = fmaf(w[j].w, h4.w, acc4.w);
        }
        float acc = (acc4.x + acc4.y) + (acc4.z + acc4.w);
        acc += __shfl_xor(acc, 1, 64);                  // pair-combine halves

        __syncthreads();   // all LDS h reads for step t done

        if (active && p == 0) {
            float z  = acc + aval;
            float hn = 1.f / (1.f + __expf(-z));
            hbuf[r] = hn;
            bp[t * 300 + r] = hn;                       // overwrite A with h
            if (t == T_ - 1) hfinal[b * 300 + r] = hn;
        }
        __syncthreads();   // h ready for step t+1
    }
}

// ---------------------------------------------------------------------------
// K3: in-place out = h @ W2^T + b2 over buf. Each block owns 64 full rows:
// stage h rows to LDS, then compute all 300 outputs per row and overwrite.
// 256 threads: thread = (ty = tid>>4 -> 4 rows, tx = tid&15 -> 19 n-slots).
// ---------------------------------------------------------------------------
__global__ __launch_bounds__(256) void out_gemm_inplace_kernel(
    float* __restrict__ buf,
    const float* __restrict__ W2,   // [300][300]
    const float* __restrict__ b2)   // [300]
{
    __shared__ float hs[64][305];
    __shared__ float ws[16][305];
    const int tid = threadIdx.x;
    const int tx = tid & 15;
    const int ty = tid >> 4;
    float* base = buf + (size_t)blockIdx.x * 64 * 300;

    // stage 64 h rows
    for (int e = tid; e < 64 * 300; e += 256) {
        int rr = e / 300, cc = e - rr * 300;
        hs[rr][cc] = base[rr * 300 + cc];
    }
    // zero pads
    for (int e = tid; e < 64 * 5; e += 256) {
        int rr = e / 5;
        hs[rr][300 + (e - rr * 5)] = 0.f;
    }
    if (tid < 80) ws[tid / 5][300 + (tid % 5)] = 0.f;

    float acc[4][19] = {};

    for (int kc = 0; kc < 300; kc += 16) {
        __syncthreads();   // previous chunk's reads complete / staging visible
        // load W2 chunk: ws[k][n] = W2[n][kc+k], k<16, n<300
        for (int e = tid; e < 300 * 16; e += 256) {
            int n = e >> 4;
            int k = e & 15;
            int gk = kc + k;
            ws[k][n] = (gk < 300) ? W2[(size_t)n * 300 + gk] : 0.f;
        }
        __syncthreads();
        #pragma unroll
        for (int k = 0; k < 16; ++k) {
            float hv[4];
            #pragma unroll
            for (int i = 0; i < 4; ++i) hv[i] = hs[ty * 4 + i][kc + k];
            #pragma unroll
            for (int jj = 0; jj < 19; ++jj) {
                float wv = ws[k][tx + 16 * jj];
                #pragma unroll
                for (int i = 0; i < 4; ++i)
                    acc[i][jj] = fmaf(hv[i], wv, acc[i][jj]);
            }
        }
    }

    // overwrite rows with outputs (all LDS reads of hs/ws for compute done)
    #pragma unroll
    for (int i = 0; i < 4; ++i) {
        int rr = ty * 4 + i;
        #pragma unroll
        for (int jj = 0; jj < 19; ++jj) {
            int n = tx + 16 * jj;
            if (n < 300) base[rr * 300 + n] = acc[i][jj] + b2[n];
        }
    }
}

// ---------------------------------------------------------------------------
extern "C" void kernel_launch(void* const* d_in, const int* in_sizes, int n_in,
                              void* d_out, int out_size, void* d_ws, size_t ws_size,
                              hipStream_t stream)
{
    const float* x  = (const float*)d_in[0];   // [128][1024][300]
    const float* W1 = (const float*)d_in[1];   // [300][600]
    const float* b1 = (const float*)d_in[2];   // [300]
    const float* W2 = (const float*)d_in[3];   // [300][300]
    const float* b2 = (const float*)d_in[4];   // [300]

    float* out    = (float*)d_out;                       // [128][1024][300]
    float* hfinal = out + (size_t)B_ * T_ * OUT_;        // [128][300]

    // K1: A = x @ W1x^T + b1  -> into out buffer
    dim3 g1(131072 / 64, 5);
    gemm_bias_kernel<<<g1, 256, 0, stream>>>(x, IN_, W1, 600, 0, b1,
                                             out, H_, H_, IN_);

    // K2: recurrence, A -> h in place, also writes hfinal
    elman_rec_kernel<<<B_, 640, 0, stream>>>(W1, out, hfinal);

    // K3: out = h @ W2^T + b2, in place
    out_gemm_inplace_kernel<<<131072 / 64, 256, 0, stream>>>(out, W2, b2);
}

// Round 3
// 2112.060 us; speedup vs baseline: 2.1737x; 2.1737x over previous
//
#include <hip/hip_runtime.h>

typedef __attribute__((ext_vector_type(4))) float f32x4;
typedef __attribute__((ext_vector_type(8))) short bf16x8;

#define B_   128
#define T_   1024
#define NROW 131072      // B*T
#define HB   (NROW*300)  // floats in the [B*T][300] matrix

__device__ inline unsigned short f2bf(float f) {
    union { float f; unsigned int u; } v; v.f = f;
    unsigned int r = v.u + 0x7FFFu + ((v.u >> 16) & 1u);
    return (unsigned short)(r >> 16);
}

// Load up to 8 consecutive f32 (zero-masked at K=300 boundary), convert to bf16,
// return packed uint4 (8 bf16, fragment j-order = ascending k).
__device__ inline uint4 load8_cvt(const float* src, bool rowok, int krem) {
    f32x4 v0 = {0.f,0.f,0.f,0.f}, v1 = {0.f,0.f,0.f,0.f};
    if (rowok) {
        if (krem >= 8)      { v0 = *(const f32x4*)src; v1 = *(const f32x4*)(src + 4); }
        else if (krem >= 4) { v0 = *(const f32x4*)src; }
    }
    uint4 p;
    p.x = (unsigned)f2bf(v0[0]) | ((unsigned)f2bf(v0[1]) << 16);
    p.y = (unsigned)f2bf(v0[2]) | ((unsigned)f2bf(v0[3]) << 16);
    p.z = (unsigned)f2bf(v1[0]) | ((unsigned)f2bf(v1[1]) << 16);
    p.w = (unsigned)f2bf(v1[2]) | ((unsigned)f2bf(v1[3]) << 16);
    return p;
}

// ---------------------------------------------------------------------------
// K1: A[m][n] = sum_k X[m][k]*W1[n][k] + b1[n]   (bf16 MFMA, f32 out)
// Block: 256 thr (4 waves), BM=128 (8 M-tiles, 2/wave), BN=160 (10 N-tiles),
// K padded 300->320, BK=32. Grid (1024, 2). No in-place hazard: reads X,
// writes A — disjoint buffers, disjoint n-ranges across blockIdx.y.
// ---------------------------------------------------------------------------
__global__ __launch_bounds__(256) void gemm_in(
    const float* __restrict__ X, const float* __restrict__ W1,
    const float* __restrict__ b1, float* __restrict__ A)
{
    __shared__ unsigned short alds[8 * 64 * 8];    // frag-linear x tile
    __shared__ unsigned short blds[10 * 64 * 8];   // frag-linear W tile
    const int tid = threadIdx.x;
    const int w = tid >> 6, l = tid & 63, lg = l >> 4, ln = l & 15;
    const size_t m0 = (size_t)blockIdx.x * 128;
    const int n0 = blockIdx.y * 160;

    f32x4 acc[2][10];
    #pragma unroll
    for (int q = 0; q < 2; ++q)
        #pragma unroll
        for (int nt = 0; nt < 10; ++nt) acc[q][nt] = (f32x4){0.f,0.f,0.f,0.f};

    for (int kt = 0; kt < 10; ++kt) {
        const int kc = kt * 32;
        __syncthreads();
        // stage X tile: 128 rows x 32 k -> frag-linear
        #pragma unroll
        for (int rep = 0; rep < 2; ++rep) {
            int e = tid + rep * 256;            // < 512
            int row = e >> 2, kh = e & 3;
            int k0 = kc + kh * 8;
            uint4 p = load8_cvt(X + (m0 + row) * 300 + k0, true, 300 - k0);
            *(uint4*)&alds[(((row >> 4) * 64) + kh * 16 + (row & 15)) * 8] = p;
        }
        // stage W tile: 160 n-rows x 32 k
        #pragma unroll
        for (int rep = 0; rep < 3; ++rep) {
            int e = tid + rep * 256;
            if (e < 640) {
                int nn = e >> 2, kh = e & 3;
                int n = n0 + nn;
                int k0 = kc + kh * 8;
                uint4 p = load8_cvt(W1 + (size_t)n * 600 + k0, n < 300, 300 - k0);
                *(uint4*)&blds[(((nn >> 4) * 64) + kh * 16 + (nn & 15)) * 8] = p;
            }
        }
        __syncthreads();
        bf16x8 bfr[10];
        #pragma unroll
        for (int nt = 0; nt < 10; ++nt) bfr[nt] = *(const bf16x8*)&blds[(nt * 64 + l) * 8];
        #pragma unroll
        for (int q = 0; q < 2; ++q) {
            bf16x8 afr = *(const bf16x8*)&alds[((w * 2 + q) * 64 + l) * 8];
            #pragma unroll
            for (int nt = 0; nt < 10; ++nt)
                acc[q][nt] = __builtin_amdgcn_mfma_f32_16x16x32_bf16(afr, bfr[nt], acc[q][nt], 0, 0, 0);
        }
    }

    #pragma unroll
    for (int q = 0; q < 2; ++q)
        #pragma unroll
        for (int nt = 0; nt < 10; ++nt) {
            int n = n0 + nt * 16 + ln;
            if (n < 300) {
                float bias = b1[n];
                size_t mr = m0 + (w * 2 + q) * 16 + lg * 4;
                #pragma unroll
                for (int i = 0; i < 4; ++i)
                    A[(mr + i) * 300 + n] = acc[q][nt][i] + bias;
            }
        }
}

// ---------------------------------------------------------------------------
// K2: recurrence with MFMA. 8 blocks x 512 thr (8 waves). Block owns 16 batches.
// W1h (bf16) lives in VGPR A-fragments: waves 0-3 own 3 M-tiles, waves 4-7 own 2
// (20 tiles = M 320). h exchanged via double-buffered LDS B-fragments (1 barrier
// per step). A_pre f32 rows in `buf` are consumed and overwritten (one step
// delayed) with bf16-packed h rows: row m -> byte (m>>6)*76800 + (m&63)*600.
// Race-free: packed store at time tt clobbers f32 bytes of times <= tt only;
// prefetch reads time t+1 = tt+2; barrier each step keeps lanes in lockstep.
// ---------------------------------------------------------------------------
__global__ __launch_bounds__(512, 2) void elman_rec_mfma(
    const float* __restrict__ W1, float* __restrict__ buf,
    float* __restrict__ hfinal)
{
    __shared__ unsigned short hlds[2][10 * 64 * 8];   // 2 x 10KB
    const int tid = threadIdx.x;
    const int w = tid >> 6, l = tid & 63, lg = l >> 4, ln = l & 15;
    const bool w4 = (w < 4);
    const int b0 = blockIdx.x * 16;
    const int bb = b0 + ln;                 // this lane's batch (B/C column)

    int rq[3], ldsidx[3];
    #pragma unroll
    for (int q = 0; q < 3; ++q) {
        int tile = w4 ? (3 * w + q) : (12 + 2 * (w - 4) + q);
        int r = tile * 16 + 4 * lg;
        rq[q] = r;
        ldsidx[q] = ((r >> 5) * 64 + ((r >> 3) & 3) * 16 + ln) * 8 + (r & 7);
    }

    // Load W1h A-fragments into registers (rows >=300 and k>=300 zeroed).
    bf16x8 afrag[3][10];
    #pragma unroll
    for (int q = 0; q < 3; ++q) {
        #pragma unroll
        for (int kt = 0; kt < 10; ++kt) {
            bool qa = (q < 2) || w4;
            int tile = w4 ? (3 * w + q) : (12 + 2 * (w - 4) + q);
            int r = tile * 16 + ln;
            int k0 = kt * 32 + lg * 8;
            uint4 p = load8_cvt(W1 + (size_t)r * 600 + 300 + k0,
                                qa && r < 300, 300 - k0);
            union { uint4 u; bf16x8 s; } cv; cv.u = p;
            afrag[q][kt] = cv.s;
        }
    }

    for (int i = tid; i < 10 * 64 * 8; i += 512) hlds[0][i] = 0;

    // initial A_pre load (t=0)
    f32x4 Acur[3];
    {
        const float* ar = buf + (size_t)bb * 1024 * 300;
        #pragma unroll
        for (int q = 0; q < 3; ++q)
            if ((q < 2) || w4) Acur[q] = *(const f32x4*)(ar + rq[q]);
    }
    uint2 hp[3];
    __syncthreads();

    for (int t = 0; t < T_; ++t) {
        const int cur = t & 1, nxt = cur ^ 1;

        // prefetch A_pre for t+1
        f32x4 Anext[3];
        if (t < T_ - 1) {
            const float* ar = buf + ((size_t)bb * 1024 + t + 1) * 300;
            #pragma unroll
            for (int q = 0; q < 3; ++q)
                if ((q < 2) || w4) Anext[q] = *(const f32x4*)(ar + rq[q]);
        }

        // delayed packed-h global store for step t-1 (race-free vs A reads)
        if (t > 0) {
            int tt = t - 1;
            char* pb = (char*)buf;
            size_t gb = (size_t)(bb * 16 + (tt >> 6)) * 76800 + (size_t)(tt & 63) * 600;
            #pragma unroll
            for (int q = 0; q < 3; ++q)
                if (((q < 2) || w4) && rq[q] < 300)
                    *(uint2*)(pb + gb + rq[q] * 2) = hp[q];
        }

        // MFMA: acc = W1h (A-frags) x h (B-frags from LDS)
        f32x4 acc[3];
        #pragma unroll
        for (int q = 0; q < 3; ++q) acc[q] = (f32x4){0.f,0.f,0.f,0.f};
        #pragma unroll
        for (int kt = 0; kt < 10; ++kt) {
            bf16x8 bfr = *(const bf16x8*)&hlds[cur][(kt * 64 + l) * 8];
            acc[0] = __builtin_amdgcn_mfma_f32_16x16x32_bf16(afrag[0][kt], bfr, acc[0], 0, 0, 0);
            acc[1] = __builtin_amdgcn_mfma_f32_16x16x32_bf16(afrag[1][kt], bfr, acc[1], 0, 0, 0);
            if (w4)
                acc[2] = __builtin_amdgcn_mfma_f32_16x16x32_bf16(afrag[2][kt], bfr, acc[2], 0, 0, 0);
        }

        // sigmoid + pack + LDS write (next buffer) + hfinal at t=1023
        #pragma unroll
        for (int q = 0; q < 3; ++q) {
            if (q == 2 && !w4) continue;
            f32x4 hv;
            #pragma unroll
            for (int i = 0; i < 4; ++i) {
                float z = acc[q][i] + Acur[q][i];
                hv[i] = 1.f / (1.f + __expf(-z));
            }
            if (rq[q] >= 300) hv = (f32x4){0.f,0.f,0.f,0.f};
            uint2 p;
            p.x = (unsigned)f2bf(hv[0]) | ((unsigned)f2bf(hv[1]) << 16);
            p.y = (unsigned)f2bf(hv[2]) | ((unsigned)f2bf(hv[3]) << 16);
            hp[q] = p;
            *(uint2*)&hlds[nxt][ldsidx[q]] = p;
            if (t == T_ - 1 && rq[q] < 300)
                *(f32x4*)(hfinal + bb * 300 + rq[q]) = hv;
        }

        if (t < T_ - 1) {
            #pragma unroll
            for (int q = 0; q < 3; ++q)
                if ((q < 2) || w4) Acur[q] = Anext[q];
        }
        __syncthreads();
    }

    // tail: packed store for t=1023
    {
        int tt = T_ - 1;
        char* pb = (char*)buf;
        size_t gb = (size_t)(bb * 16 + (tt >> 6)) * 76800 + (size_t)(tt & 63) * 600;
        #pragma unroll
        for (int q = 0; q < 3; ++q)
            if (((q < 2) || w4) && rq[q] < 300)
                *(uint2*)(pb + gb + rq[q] * 2) = hp[q];
    }
}

// ---------------------------------------------------------------------------
// K3: out[m][n] = sum_k h[m][k]*W2[n][k] + b2[n], in place over packed-h buf.
// RACE FIX vs prev round: one block per 64-row chunk (grid 2048), block computes
// ALL 300 output columns, so the packed bytes a block reads are written only by
// that block, and only after its final global read (barrier separated).
// 256 thr (4 waves): wave w owns M-tile w (16 rows) x 19 N-tiles (BN=304).
// ---------------------------------------------------------------------------
__global__ __launch_bounds__(256) void gemm_out(
    float* __restrict__ buf, const float* __restrict__ W2,
    const float* __restrict__ b2)
{
    __shared__ unsigned short alds[4 * 64 * 8];    // 4 KB packed-h tile
    __shared__ unsigned short blds[19 * 64 * 8];   // 19 KB W2 tile
    const int tid = threadIdx.x;
    const int w = tid >> 6, l = tid & 63, lg = l >> 4, ln = l & 15;
    const size_t chunk = blockIdx.x;               // 64-row chunk
    const char* pbase = (const char*)buf + chunk * 76800;

    f32x4 acc[19];
    #pragma unroll
    for (int nt = 0; nt < 19; ++nt) acc[nt] = (f32x4){0.f,0.f,0.f,0.f};

    for (int kt = 0; kt < 10; ++kt) {
        const int kc = kt * 32;
        __syncthreads();
        // stage packed bf16 h tile: 64 rows x 32 k, one entry per thread
        {
            int row = tid >> 2, kh = tid & 3;
            int k0 = kc + kh * 8;
            const char* p = pbase + row * 600;
            uint2 lo = make_uint2(0u, 0u), hi = make_uint2(0u, 0u);
            int krem = 300 - k0;
            if (krem >= 8)      { lo = *(const uint2*)(p + k0 * 2); hi = *(const uint2*)(p + k0 * 2 + 8); }
            else if (krem >= 4) { lo = *(const uint2*)(p + k0 * 2); }
            uint4 pk; pk.x = lo.x; pk.y = lo.y; pk.z = hi.x; pk.w = hi.y;
            *(uint4*)&alds[(((row >> 4) * 64) + kh * 16 + (row & 15)) * 8] = pk;
        }
        // stage W2 tile: 304 n-rows x 32 k
        #pragma unroll
        for (int rep = 0; rep < 5; ++rep) {
            int e = tid + rep * 256;
            if (e < 1216) {
                int nn = e >> 2, kh = e & 3;
                int k0 = kc + kh * 8;
                uint4 p = load8_cvt(W2 + (size_t)nn * 300 + k0, nn < 300, 300 - k0);
                *(uint4*)&blds[(((nn >> 4) * 64) + kh * 16 + (nn & 15)) * 8] = p;
            }
        }
        __syncthreads();
        bf16x8 afr = *(const bf16x8*)&alds[(w * 64 + l) * 8];
        #pragma unroll
        for (int nt = 0; nt < 19; ++nt) {
            bf16x8 bfr = *(const bf16x8*)&blds[(nt * 64 + l) * 8];
            acc[nt] = __builtin_amdgcn_mfma_f32_16x16x32_bf16(afr, bfr, acc[nt], 0, 0, 0);
        }
    }

    // overwrite chunk with f32 outputs (all global packed reads are done:
    // they complete before the last __syncthreads that published LDS tiles)
    float* frow = buf + chunk * 19200;             // 64 rows * 300 cols
    #pragma unroll
    for (int nt = 0; nt < 19; ++nt) {
        int n = nt * 16 + ln;
        if (n < 300) {
            float bias = b2[n];
            int mr = w * 16 + lg * 4;
            #pragma unroll
            for (int i = 0; i < 4; ++i)
                frow[(mr + i) * 300 + n] = acc[nt][i] + bias;
        }
    }
}

// ---------------------------------------------------------------------------
extern "C" void kernel_launch(void* const* d_in, const int* in_sizes, int n_in,
                              void* d_out, int out_size, void* d_ws, size_t ws_size,
                              hipStream_t stream)
{
    const float* x  = (const float*)d_in[0];
    const float* W1 = (const float*)d_in[1];
    const float* b1 = (const float*)d_in[2];
    const float* W2 = (const float*)d_in[3];
    const float* b2 = (const float*)d_in[4];

    float* out    = (float*)d_out;
    float* hfinal = out + (size_t)HB;

    gemm_in<<<dim3(1024, 2), 256, 0, stream>>>(x, W1, b1, out);
    elman_rec_mfma<<<8, 512, 0, stream>>>(W1, out, hfinal);
    gemm_out<<<2048, 256, 0, stream>>>(out, W2, b2);
}